// Round 16
// baseline (107.212 us; speedup 1.0000x reference)
//
#include <hip/hip_runtime.h>

#define NJ 24
#define NF 7
#define FS 6
#define THREADS 128  // 2 waves/block; each thread computes 2 samples
#define CUNITS 12    // float4 per thread per chunk (4 joint-pairs = 192 B)
#define PAD 13       // LDS stride in float4 units

typedef float v4f __attribute__((ext_vector_type(4)));

// parent of each joint; parents[i] < i, so sequential order is topological
__device__ constexpr int kParents[NJ] = {-1, 0, 0, 0, 1, 2, 3, 4, 5, 6, 7, 8,
                                          9, 9, 9, 12, 13, 14, 16, 17, 18, 19, 20, 21};

// Dual-sample joint: ONE set of weight s_loads (CSE'd) feeds TWO independent
// fmaf chains -> per-CU scalar-memory traffic halves vs 1 sample/thread.
#define JOINT2(i)                                                             \
    {                                                                         \
        const int p_ = kParents[i];                                           \
        float inA_[NF], inB_[NF];                                             \
        inA_[0] = xrA[i]; inB_[0] = xrB[i];                                   \
        _Pragma("unroll")                                                     \
        for (int j = 0; j < FS; ++j) {                                        \
            inA_[1 + j] = (p_ < 0) ? 0.0f : fA[(p_ < 0) ? 0 : p_][j];         \
            inB_[1 + j] = (p_ < 0) ? 0.0f : fB[(p_ < 0) ? 0 : p_][j];         \
        }                                                                     \
        float hA_[NF], hB_[NF];                                               \
        _Pragma("unroll")                                                     \
        for (int j = 0; j < NF; ++j) {                                        \
            const float bv_ = b1[(i) * NF + j];                               \
            hA_[j] = bv_; hB_[j] = bv_;                                       \
        }                                                                     \
        _Pragma("unroll")                                                     \
        for (int k = 0; k < NF; ++k) {                                        \
            const float aA_ = inA_[k], aB_ = inB_[k];                         \
            _Pragma("unroll")                                                 \
            for (int j = 0; j < NF; ++j) {                                    \
                const float w_ = W1[(i) * NF * NF + k * NF + j];              \
                hA_[j] = fmaf(aA_, w_, hA_[j]);                               \
                hB_[j] = fmaf(aB_, w_, hB_[j]);                               \
            }                                                                 \
        }                                                                     \
        _Pragma("unroll")                                                     \
        for (int j = 0; j < NF; ++j) {                                        \
            hA_[j] = fmaxf(hA_[j], 0.0f); hB_[j] = fmaxf(hB_[j], 0.0f);       \
        }                                                                     \
        float fA_[FS], fB_[FS];                                               \
        _Pragma("unroll")                                                     \
        for (int j = 0; j < FS; ++j) {                                        \
            const float bv_ = b2[(i) * FS + j];                               \
            fA_[j] = bv_; fB_[j] = bv_;                                       \
        }                                                                     \
        _Pragma("unroll")                                                     \
        for (int k = 0; k < NF; ++k) {                                        \
            const float aA_ = hA_[k], aB_ = hB_[k];                           \
            _Pragma("unroll")                                                 \
            for (int j = 0; j < FS; ++j) {                                    \
                const float w_ = W2[(i) * NF * FS + k * FS + j];              \
                fA_[j] = fmaf(aA_, w_, fA_[j]);                               \
                fB_[j] = fmaf(aB_, w_, fB_[j]);                               \
            }                                                                 \
        }                                                                     \
        _Pragma("unroll")                                                     \
        for (int j = 0; j < FS; ++j) {                                        \
            fA_[j] = fmaxf(fA_[j], 0.0f); fA[i][j] = fA_[j];                  \
            fB_[j] = fmaxf(fB_[j], 0.0f); fB[i][j] = fB_[j];                  \
        }                                                                     \
        if ((i) & 1) { /* stage pair (i-1, i) for both samples */             \
            const int pp_ = ((i) >> 1) & 3;                                   \
            v4f* sA_ = myStageA + pp_ * 3;                                    \
            sA_[0] = (v4f){fA[(i) - 1][0], fA[(i) - 1][1],                    \
                           fA[(i) - 1][2], fA[(i) - 1][3]};                   \
            sA_[1] = (v4f){fA[(i) - 1][4], fA[(i) - 1][5], fA_[0], fA_[1]};   \
            sA_[2] = (v4f){fA_[2], fA_[3], fA_[4], fA_[5]};                   \
            v4f* sB_ = myStageB + pp_ * 3;                                    \
            sB_[0] = (v4f){fB[(i) - 1][0], fB[(i) - 1][1],                    \
                           fB[(i) - 1][2], fB[(i) - 1][3]};                   \
            sB_[1] = (v4f){fB[(i) - 1][4], fB[(i) - 1][5], fB_[0], fB_[1]};   \
            sB_[2] = (v4f){fB_[2], fB_[3], fB_[4], fB_[5]};                   \
        }                                                                     \
    }

// Flush chunk C for both halves: 24 ds_read_b128 into the decoupled pinned
// sets frA/frB, then 24 fire-and-forget NT stores (each = 16 full 64B lines).
#define FLUSHAB(C)                                                            \
    {                                                                         \
        _Pragma("unroll")                                                     \
        for (int j = 0; j < CUNITS; ++j) {                                    \
            const int G = j * 64 + lane;                                      \
            const int s = G / CUNITS;                                         \
            const int q = G - s * CUNITS;                                     \
            frA[j] = smA[s * PAD + q];                                        \
            frB[j] = smB[s * PAD + q];                                        \
        }                                                                     \
        _Pragma("unroll")                                                     \
        for (int j = 0; j < CUNITS; ++j)                                      \
            __builtin_nontemporal_store(frA[j], reinterpret_cast<v4f*>(       \
                obaseA + voff[j] + (C) * 192));                               \
        _Pragma("unroll")                                                     \
        for (int j = 0; j < CUNITS; ++j)                                      \
            __builtin_nontemporal_store(frB[j], reinterpret_cast<v4f*>(       \
                obaseB + voff[j] + (C) * 192));                               \
    }

#define KEEP12(A)                                                             \
    asm volatile("" :: "v"(A[0]), "v"(A[1]), "v"(A[2]), "v"(A[3]),            \
                 "v"(A[4]), "v"(A[5]), "v"(A[6]), "v"(A[7]),                  \
                 "v"(A[8]), "v"(A[9]), "v"(A[10]), "v"(A[11]));

// Requires B % 256 == 0 (bench: B = 524288 -> grid 2048).
// Block = 128 threads (2 waves) x 2 samples/thread = 256 samples.
// LDS 53248 B -> 3 blocks/CU (6 waves); per-CU s_load traffic halved.
__global__ __launch_bounds__(THREADS, 2) void se1d_kernel(
    const float* __restrict__ x,
    const float* __restrict__ W1,
    const float* __restrict__ b1,
    const float* __restrict__ W2,
    const float* __restrict__ b2,
    float* __restrict__ out, int B)
{
    // [wave][A|B][64 lanes x 13 v4f] wave-private staging; no barriers
    // (wave-synchronous; per-wave DS pipe is in-order).
    __shared__ v4f sm[2][2][64 * PAD];

    const int t    = threadIdx.x;
    const int lane = t & 63;
    const int wid  = __builtin_amdgcn_readfirstlane(threadIdx.x >> 6);
    const int base = blockIdx.x * 256;                // block's 256 samples
    const int bA   = base + wid * 64 + lane;          // A sample
    const int bB   = base + 128 + wid * 64 + lane;    // B sample
    const int wbA  = base + wid * 64;                 // wave A base (uniform)
    const int wbB  = base + 128 + wid * 64;           // wave B base (uniform)

    v4f* const myStageA = &sm[wid][0][lane * PAD];
    v4f* const myStageB = &sm[wid][1][lane * PAD];
    v4f* const smA = sm[wid][0];
    v4f* const smB = sm[wid][1];
    char* const obaseA = reinterpret_cast<char*>(
        reinterpret_cast<v4f*>(out) + (size_t)wbA * 36);
    char* const obaseB = reinterpret_cast<char*>(
        reinterpret_cast<v4f*>(out) + (size_t)wbB * 36);

    // Per-lane store byte-offsets within a wave's 36 KB output region.
    int voff[CUNITS];
    #pragma unroll
    for (int j = 0; j < CUNITS; ++j) {
        const int G = j * 64 + lane;
        const int s = G / CUNITS;
        const int q = G - s * CUNITS;
        voff[j] = (s * 36 + q) * 16;   // bytes
    }

    // ALL x up-front, NT (read-once; no mid-kernel loads behind NT stores).
    float xrA[NJ], xrB[NJ];
    {
        const v4f* xvA = reinterpret_cast<const v4f*>(x + (size_t)bA * NJ);
        const v4f* xvB = reinterpret_cast<const v4f*>(x + (size_t)bB * NJ);
        #pragma unroll
        for (int c = 0; c < NJ / 4; ++c) {
            v4f a = __builtin_nontemporal_load(xvA + c);
            v4f b = __builtin_nontemporal_load(xvB + c);
            xrA[c * 4 + 0] = a.x; xrA[c * 4 + 1] = a.y;
            xrA[c * 4 + 2] = a.z; xrA[c * 4 + 3] = a.w;
            xrB[c * 4 + 0] = b.x; xrB[c * 4 + 1] = b.y;
            xrB[c * 4 + 2] = b.z; xrB[c * 4 + 3] = b.w;
        }
    }

    float fA[NJ][FS], fB[NJ][FS];  // fully unrolled -> registers, windowed
    v4f frA[CUNITS], frB[CUNITS];  // decoupled pinned store-data sets

    JOINT2(0) JOINT2(1) JOINT2(2) JOINT2(3)
    JOINT2(4) JOINT2(5) JOINT2(6) JOINT2(7)
    FLUSHAB(0);
    JOINT2(8) JOINT2(9) JOINT2(10) JOINT2(11)
    JOINT2(12) JOINT2(13) JOINT2(14) JOINT2(15)
    FLUSHAB(1);
    JOINT2(16) JOINT2(17) JOINT2(18) JOINT2(19)
    JOINT2(20) JOINT2(21) JOINT2(22) JOINT2(23)
    FLUSHAB(2);

    KEEP12(frA);
    KEEP12(frB);
    (void)B;
}

extern "C" void kernel_launch(void* const* d_in, const int* in_sizes, int n_in,
                              void* d_out, int out_size, void* d_ws, size_t ws_size,
                              hipStream_t stream) {
    const float* x  = (const float*)d_in[0];
    const float* W1 = (const float*)d_in[1];
    const float* b1 = (const float*)d_in[2];
    const float* W2 = (const float*)d_in[3];
    const float* b2 = (const float*)d_in[4];
    float* out = (float*)d_out;
    const int B = in_sizes[0] / NJ;   // 524288, multiple of 256
    const int grid = B / 256;         // 2048
    hipLaunchKernelGGL(se1d_kernel, dim3(grid), dim3(THREADS), 0, stream,
                       x, W1, b1, W2, b2, out, B);
}

// Round 17
// 92.858 us; speedup vs baseline: 1.1546x; 1.1546x over previous
//
#include <hip/hip_runtime.h>

#define NJ 24
#define NF 7
#define FS 6
#define THREADS 256
#define CUNITS 12   // float4 per thread per chunk (4 joint-pairs = 192 B)
#define PAD 13      // LDS stride in float4 units

typedef float v4f __attribute__((ext_vector_type(4)));

// parent of each joint; parents[i] < i, so sequential order is topological
__device__ constexpr int kParents[NJ] = {-1, 0, 0, 0, 1, 2, 3, 4, 5, 6, 7, 8,
                                          9, 9, 9, 12, 13, 14, 16, 17, 18, 19, 20, 21};

// Compute joint i; stage completed joint-pairs (3 x v4f) into wave-private LDS.
#define JOINT(i)                                                              \
    {                                                                         \
        const int p_ = kParents[i];                                           \
        float inp_[NF];                                                       \
        inp_[0] = xr[i];                                                      \
        _Pragma("unroll")                                                     \
        for (int j = 0; j < FS; ++j)                                          \
            inp_[1 + j] = (p_ < 0) ? 0.0f : feats[(p_ < 0) ? 0 : p_][j];      \
        float h_[NF];                                                         \
        _Pragma("unroll")                                                     \
        for (int j = 0; j < NF; ++j) h_[j] = b1[(i) * NF + j];                \
        _Pragma("unroll")                                                     \
        for (int k = 0; k < NF; ++k) {                                        \
            const float a_ = inp_[k];                                         \
            _Pragma("unroll")                                                 \
            for (int j = 0; j < NF; ++j)                                      \
                h_[j] = fmaf(a_, W1[(i) * NF * NF + k * NF + j], h_[j]);      \
        }                                                                     \
        _Pragma("unroll")                                                     \
        for (int j = 0; j < NF; ++j) h_[j] = fmaxf(h_[j], 0.0f);              \
        float f_[FS];                                                         \
        _Pragma("unroll")                                                     \
        for (int j = 0; j < FS; ++j) f_[j] = b2[(i) * FS + j];                \
        _Pragma("unroll")                                                     \
        for (int k = 0; k < NF; ++k) {                                        \
            const float a_ = h_[k];                                           \
            _Pragma("unroll")                                                 \
            for (int j = 0; j < FS; ++j)                                      \
                f_[j] = fmaf(a_, W2[(i) * NF * FS + k * FS + j], f_[j]);      \
        }                                                                     \
        _Pragma("unroll")                                                     \
        for (int j = 0; j < FS; ++j) {                                        \
            f_[j] = fmaxf(f_[j], 0.0f);                                       \
            feats[i][j] = f_[j];                                              \
        }                                                                     \
        if ((i) & 1) {                                                        \
            const int pp_ = ((i) >> 1) & 3;                                   \
            v4f* st_ = myStage + pp_ * 3;                                     \
            st_[0] = (v4f){feats[(i) - 1][0], feats[(i) - 1][1],              \
                           feats[(i) - 1][2], feats[(i) - 1][3]};             \
            st_[1] = (v4f){feats[(i) - 1][4], feats[(i) - 1][5],              \
                           f_[0], f_[1]};                                     \
            st_[2] = (v4f){f_[2], f_[3], f_[4], f_[5]};                       \
        }                                                                     \
    }

// Flush chunk C: 12 ds_read_b128 into the persistent set fr[] (overwritten
// only one full chunk after its previous stores issued -> ample drain slack),
// then 12 fire-and-forget NT stores: SGPR base (wave-uniform) + 32-bit VGPR
// byte offset + chunk imm (+0/+192/+384 B). Each store = 16 full 64B lines.
#define FLUSH(C)                                                              \
    {                                                                         \
        _Pragma("unroll")                                                     \
        for (int j = 0; j < CUNITS; ++j) {                                    \
            const int G = j * 64 + lane;                                      \
            const int s = G / CUNITS;                                         \
            const int q = G - s * CUNITS;                                     \
            fr[j] = sm[wid][s * PAD + q];                                     \
        }                                                                     \
        _Pragma("unroll")                                                     \
        for (int j = 0; j < CUNITS; ++j) {                                    \
            v4f* dst_ = reinterpret_cast<v4f*>(                               \
                reinterpret_cast<char*>(obase) + voff[j] + (C) * 192);        \
            __builtin_nontemporal_store(fr[j], dst_);                         \
        }                                                                     \
    }

// Pin the persistent store-data set to kernel end so the allocator can't
// recycle a pending store's source reg into a compute temp (would reinsert
// store-drain vmcnt waits in the middle of compute).
#define KEEP12(A)                                                             \
    asm volatile("" :: "v"(A[0]), "v"(A[1]), "v"(A[2]), "v"(A[3]),            \
                 "v"(A[4]), "v"(A[5]), "v"(A[6]), "v"(A[7]),                  \
                 "v"(A[8]), "v"(A[9]), "v"(A[10]), "v"(A[11]));

// Requires B % 256 == 0 (bench: B = 524288).
__global__ __launch_bounds__(THREADS, 3) void se1d_kernel(
    const float* __restrict__ x,
    const float* __restrict__ W1,
    const float* __restrict__ b1,
    const float* __restrict__ W2,
    const float* __restrict__ b2,
    float* __restrict__ out, int B)
{
    // Wave-private staging: 64 lanes x 13 v4f = 13312 B/wave, 53 KB/block
    // -> 3 blocks/CU (12 waves). No barriers (wave-synchronous; per-wave DS
    // pipe is in-order).
    __shared__ v4f sm[THREADS / 64][64 * PAD];

    const int t    = threadIdx.x;
    const int lane = t & 63;
    // readfirstlane makes wid (hence wb/obase) compiler-provably uniform ->
    // stores use SADDR form: SGPR base + 32b VGPR offset.
    const int wid  = __builtin_amdgcn_readfirstlane(threadIdx.x >> 6);
    const int b    = blockIdx.x * THREADS + t;         // this thread's sample
    const int wb   = blockIdx.x * THREADS + wid * 64;  // wave base (uniform)

    v4f* const myStage = &sm[wid][lane * PAD];
    v4f* const obase = reinterpret_cast<v4f*>(out) + (size_t)wb * 36;

    // Per-lane store byte-offsets within the wave's 36 KB output region.
    int voff[CUNITS];
    #pragma unroll
    for (int j = 0; j < CUNITS; ++j) {
        const int G = j * 64 + lane;
        const int s = G / CUNITS;
        const int q = G - s * CUNITS;
        voff[j] = (s * 36 + q) * 16;   // bytes
    }

    // ALL x loaded up-front, non-temporal (read-once stream; mid-kernel loads
    // would vmcnt-wait on older NT stores).
    float xr[NJ];
    {
        const v4f* xv = reinterpret_cast<const v4f*>(x + (size_t)b * NJ);
        #pragma unroll
        for (int c = 0; c < NJ / 4; ++c) {
            v4f v = __builtin_nontemporal_load(xv + c);
            xr[c * 4 + 0] = v.x; xr[c * 4 + 1] = v.y;
            xr[c * 4 + 2] = v.z; xr[c * 4 + 3] = v.w;
        }
    }

    float feats[NJ][FS];  // fully unrolled -> registers, ~3 joints live
    v4f fr[CUNITS];       // persistent decoupled store-data set (pinned)

    // chunk 0
    JOINT(0) JOINT(1) JOINT(2) JOINT(3) JOINT(4) JOINT(5) JOINT(6) JOINT(7)
    FLUSH(0);
    // chunk 1 (fr overwrite waits only on chunk-0's oldest store: ~5Kcyc old)
    JOINT(8) JOINT(9) JOINT(10) JOINT(11)
    JOINT(12) JOINT(13) JOINT(14) JOINT(15)
    FLUSH(1);
    // chunk 2
    JOINT(16) JOINT(17) JOINT(18) JOINT(19)
    JOINT(20) JOINT(21) JOINT(22) JOINT(23)
    FLUSH(2);

    KEEP12(fr);
    (void)B;
}

extern "C" void kernel_launch(void* const* d_in, const int* in_sizes, int n_in,
                              void* d_out, int out_size, void* d_ws, size_t ws_size,
                              hipStream_t stream) {
    const float* x  = (const float*)d_in[0];
    const float* W1 = (const float*)d_in[1];
    const float* b1 = (const float*)d_in[2];
    const float* W2 = (const float*)d_in[3];
    const float* b2 = (const float*)d_in[4];
    float* out = (float*)d_out;
    const int B = in_sizes[0] / NJ;   // 524288, multiple of 256
    const int grid = B / THREADS;
    hipLaunchKernelGGL(se1d_kernel, dim3(grid), dim3(THREADS), 0, stream,
                       x, W1, b1, W2, b2, out, B);
}